// Round 5
// baseline (422.345 us; speedup 1.0000x reference)
//
#include <hip/hip_runtime.h>

// SLAYER constants
#define ALPHA  0.90483741803595952f   /* exp(-1/10) */
#define ALPHA8 0.44932896411722156f   /* exp(-0.8)  */
#define THETA  10.0f
#define BF1    ((unsigned short)0x3F80) /* 1.0f as bf16 */

typedef short   bf16x8 __attribute__((ext_vector_type(8)));
typedef float   f32x4  __attribute__((ext_vector_type(4)));
typedef float   f32x4v __attribute__((ext_vector_type(4)));
typedef unsigned short ushort4v __attribute__((ext_vector_type(4)));
typedef unsigned short ushort8v __attribute__((ext_vector_type(8)));

// RNE float -> bf16 bits
__device__ __forceinline__ unsigned short f2bf(float f) {
    unsigned int x = __float_as_uint(f);
    unsigned int r = (x + 0x7FFFu + ((x >> 16) & 1u)) >> 16;
    return (unsigned short)r;
}
__device__ __forceinline__ float bf2f(unsigned short h) {
    return __uint_as_float(((unsigned int)h) << 16);
}
// 2-way bf16 split: w ~= h0+h1 (residual ~2^-17 rel; spikes have huge margin)
__device__ __forceinline__ void split2(float w, unsigned short& h0,
                                       unsigned short& h1) {
    h0 = f2bf(w);          float r0 = w - bf2f(h0);
    h1 = f2bf(r0);
}

// ---------------------------------------------------------------------------
// Prep: In fp32 [32][156][2048] -> Inbf ushort [32*156][2048] (row-major bf16)
//                               -> InT  ushort [32][2048][160] (transposed, c pad 160)
// ---------------------------------------------------------------------------
__global__ __launch_bounds__(256) void prep_in(
    const float* __restrict__ In, unsigned short* __restrict__ Inbf,
    unsigned short* __restrict__ InT)
{
    __shared__ float Tile[64][65];
    const int t0 = blockIdx.x * 64;
    const int c0 = blockIdx.y * 64;
    const int b  = blockIdx.z;
    const int tid = threadIdx.x;

    #pragma unroll
    for (int s = 0; s < 4; ++s) {
        int id = tid + s * 256;
        int cc = id >> 4;
        int t4 = (id & 15) * 4;
        f32x4v v = {0.f, 0.f, 0.f, 0.f};
        if (c0 + cc < 156)
            v = *(const f32x4v*)(In + ((long long)(b * 156 + c0 + cc) * 2048 + t0 + t4));
        *(f32x4v*)&Tile[cc][t4] = v;
    }
    __syncthreads();

    #pragma unroll
    for (int s = 0; s < 2; ++s) {
        int id = tid + s * 256;
        int t  = id >> 3;
        int c8 = (id & 7) * 8;
        unsigned short r[8];
        #pragma unroll
        for (int j = 0; j < 8; ++j) r[j] = f2bf(Tile[c8 + j][t]);
        *(ushort8v*)(InT + (long long)b * 327680 + (long long)(t0 + t) * 160 + c0 + c8)
            = *(ushort8v*)r;
    }
    #pragma unroll
    for (int s = 0; s < 2; ++s) {
        int id = tid + s * 256;
        int cc = id >> 3;
        int t8 = (id & 7) * 8;
        if (c0 + cc < 156) {
            unsigned short r[8];
            #pragma unroll
            for (int j = 0; j < 8; ++j) r[j] = f2bf(Tile[cc][t8 + j]);
            *(ushort8v*)(Inbf + (long long)(b * 156 + c0 + cc) * 2048 + t0 + t8)
                = *(ushort8v*)r;
        }
    }
}

// ---------------------------------------------------------------------------
// Pack a weight matrix [M][K] fp32 into 2 bf16 split planes [2][Mp][Kp].
// ---------------------------------------------------------------------------
__global__ __launch_bounds__(256) void pack2_w(
    const float* __restrict__ W, unsigned short* __restrict__ P,
    int M, int K, int Kp)
{
    const int m = blockIdx.x;
    const int Mp = gridDim.x;
    for (int k = threadIdx.x; k < Kp; k += 256) {
        float v = (m < M && k < K) ? W[(long long)m * K + k] : 0.f;
        unsigned short h0, h1;
        split2(v, h0, h1);
        P[(long long)m * Kp + k] = h0;
        P[(long long)Mp * Kp + (long long)m * Kp + k] = h1;
    }
}

// ---------------------------------------------------------------------------
// Branch-1 GEMM1 (MFMA, packed split-2):
//   D1[z][m][n] = sum_c W1[m][c] * In[b0+z][c][n],  M=512, N=2048, K=160
// Tile 128x128, BK=32, 5 iters. grid (16 n, 4 m, 16 z).
// ---------------------------------------------------------------------------
__global__ __launch_bounds__(256) void gemm1_mfma(
    const unsigned short* __restrict__ W1p,
    const unsigned short* __restrict__ InT,
    float* __restrict__ D1, int b0)
{
    __shared__ alignas(16) unsigned short As[2][128][40];
    __shared__ alignas(16) unsigned short Bs[128][40];

    const int z  = blockIdx.z;
    const int m0 = blockIdx.y * 128;
    const int n0 = blockIdx.x * 128;
    const int tid  = threadIdx.x;
    const int lane = tid & 63, w = tid >> 6;
    const int wy = w >> 1, wx = w & 1;
    const int l15 = lane & 15, kq = lane >> 4;

    const unsigned short* Tb = InT + (long long)(b0 + z) * 327680;

    f32x4 acc[4][4] = {};

    for (int k0 = 0; k0 < 160; k0 += 32) {
        #pragma unroll
        for (int s = 0; s < 4; ++s) {
            int id = tid + s * 256;
            int pl = id >> 9, rem = id & 511;
            int m = rem >> 2, k8 = (rem & 3) * 8;
            ushort8v v = *(const ushort8v*)(W1p + (long long)pl * 81920 +
                                            (long long)(m0 + m) * 160 + k0 + k8);
            *(ushort8v*)&As[pl][m][k8] = v;
        }
        #pragma unroll
        for (int s = 0; s < 2; ++s) {
            int id = tid + s * 256;
            int t = id >> 2, c8 = (id & 3) * 8;
            ushort8v v = *(const ushort8v*)(Tb + (long long)(n0 + t) * 160 + k0 + c8);
            *(ushort8v*)&Bs[t][c8] = v;
        }
        __syncthreads();

        bf16x8 bfr[4];
        #pragma unroll
        for (int nt = 0; nt < 4; ++nt)
            bfr[nt] = *(const bf16x8*)&Bs[wx * 64 + nt * 16 + l15][kq * 8];
        #pragma unroll
        for (int s = 0; s < 2; ++s) {
            #pragma unroll
            for (int mt = 0; mt < 4; ++mt) {
                bf16x8 afr = *(const bf16x8*)&As[s][wy * 64 + mt * 16 + l15][kq * 8];
                #pragma unroll
                for (int nt = 0; nt < 4; ++nt)
                    acc[mt][nt] = __builtin_amdgcn_mfma_f32_16x16x32_bf16(
                        afr, bfr[nt], acc[mt][nt], 0, 0, 0);
            }
        }
        __syncthreads();
    }

    float* Db = D1 + (long long)z * 512 * 2048;
    #pragma unroll
    for (int mt = 0; mt < 4; ++mt) {
        #pragma unroll
        for (int i = 0; i < 4; ++i) {
            int m = m0 + wy * 64 + mt * 16 + kq * 4 + i;
            #pragma unroll
            for (int nt = 0; nt < 4; ++nt) {
                int n = n0 + wx * 64 + nt * 16 + l15;
                Db[(long long)m * 2048 + n] = acc[mt][nt][i];
            }
        }
    }
}

// ---------------------------------------------------------------------------
// Branch-2 GEMM1 (MFMA, packed split-2), batch merged into N, SPLIT-K x4:
//   Zp[s][m][n] = sum_{k in slice s} Wl1[m][k] * InF[n][k]
//   M=512, N=4992, K=2048 (4 slices of 512).
// Tile 64m x 64n, BK=64. grid (78, 8, 4) = 2496 blocks.
// ---------------------------------------------------------------------------
__global__ __launch_bounds__(256) void gemmL1_mfma(
    const unsigned short* __restrict__ Wl1p,  // [2][512][2048]
    const unsigned short* __restrict__ InF,   // [4992][2048] bf16
    float* __restrict__ Zp)                   // [4][32][512][156]
{
    __shared__ alignas(16) unsigned short As[2][64][72];
    __shared__ alignas(16) unsigned short Bs[64][72];

    const int n0  = blockIdx.x * 64;
    const int m0  = blockIdx.y * 64;
    const int ks0 = blockIdx.z * 512;
    const int tid  = threadIdx.x;
    const int lane = tid & 63, w = tid >> 6;
    const int wy = w >> 1, wx = w & 1;
    const int l15 = lane & 15, kq = lane >> 4;

    f32x4 acc[2][2] = {};

    for (int kk = 0; kk < 512; kk += 64) {
        const int k0 = ks0 + kk;
        // A: 2 planes x 64m x 64k = 1024 ushort8 chunks, 4/thread
        #pragma unroll
        for (int s = 0; s < 4; ++s) {
            int id = tid + s * 256;
            int pl = id >> 9, rem = id & 511;
            int m = rem >> 3, k8 = (rem & 7) * 8;
            ushort8v v = *(const ushort8v*)(Wl1p + (long long)pl * 1048576 +
                                            (long long)(m0 + m) * 2048 + k0 + k8);
            *(ushort8v*)&As[pl][m][k8] = v;
        }
        // B: 64n x 64k = 512 chunks, 2/thread (rows k-contiguous)
        #pragma unroll
        for (int s = 0; s < 2; ++s) {
            int id = tid + s * 256;
            int n = id >> 3, k8 = (id & 7) * 8;
            ushort8v v = *(const ushort8v*)(InF + (long long)(n0 + n) * 2048 + k0 + k8);
            *(ushort8v*)&Bs[n][k8] = v;
        }
        __syncthreads();

        #pragma unroll
        for (int ks = 0; ks < 2; ++ks) {
            bf16x8 bfr[2];
            #pragma unroll
            for (int nt = 0; nt < 2; ++nt)
                bfr[nt] = *(const bf16x8*)&Bs[wx * 32 + nt * 16 + l15][ks * 32 + kq * 8];
            #pragma unroll
            for (int s = 0; s < 2; ++s) {
                #pragma unroll
                for (int mt = 0; mt < 2; ++mt) {
                    bf16x8 afr = *(const bf16x8*)&As[s][wy * 32 + mt * 16 + l15][ks * 32 + kq * 8];
                    #pragma unroll
                    for (int nt = 0; nt < 2; ++nt)
                        acc[mt][nt] = __builtin_amdgcn_mfma_f32_16x16x32_bf16(
                            afr, bfr[nt], acc[mt][nt], 0, 0, 0);
                }
            }
        }
        __syncthreads();
    }

    float* Zs = Zp + (long long)blockIdx.z * 2555904;
    #pragma unroll
    for (int mt = 0; mt < 2; ++mt) {
        #pragma unroll
        for (int i = 0; i < 4; ++i) {
            int m = m0 + wy * 32 + mt * 16 + kq * 4 + i;
            #pragma unroll
            for (int nt = 0; nt < 2; ++nt) {
                int n = n0 + wx * 32 + nt * 16 + l15;
                int bb = n / 156, cc = n - bb * 156;
                Zs[((long long)bb * 512 + m) * 156 + cc] = acc[mt][nt][i];
            }
        }
    }
}

// ---------------------------------------------------------------------------
// GEMM2 (MFMA, packed split-2 A, optional split-K via blockIdx.y):
//   Cpart[y][b][m][n] = sum_{k in slice y} A[m][k] * Bsp[b][k][n]
// Tile 32m x 128n, BK=64.
// ---------------------------------------------------------------------------
__global__ __launch_bounds__(256) void gemm2_mfma(
    const unsigned short* __restrict__ Ap,
    const unsigned short* __restrict__ Bsp,
    float* __restrict__ C,
    int N, int ldb, long long bStrideB, long long cStride,
    int kPerSlice, long long partStride)
{
    __shared__ alignas(16) unsigned short As[2][32][72];
    __shared__ alignas(16) unsigned short Bs[128][72];

    const int b   = blockIdx.z;
    const int n0  = blockIdx.x * 128;
    const int ks0 = blockIdx.y * kPerSlice;
    const int tid  = threadIdx.x;
    const int lane = tid & 63, w = tid >> 6;
    const int l15 = lane & 15, kq = lane >> 4;

    const unsigned short* Bb = Bsp + (long long)b * bStrideB;

    f32x4 acc[2][2] = {};

    for (int kk = 0; kk < kPerSlice; kk += 64) {
        const int k0 = ks0 + kk;
        #pragma unroll
        for (int s = 0; s < 2; ++s) {
            int id = tid + s * 256;
            int pl = id >> 8, rem = id & 255;
            int m = rem >> 3, k8 = (rem & 7) * 8;
            ushort8v v = *(const ushort8v*)(Ap + (long long)pl * 16384 +
                                            (long long)m * 512 + k0 + k8);
            *(ushort8v*)&As[pl][m][k8] = v;
        }
        {
            int kb = (tid >> 4) * 4;
            int nb = (tid & 15) * 8;
            unsigned short rv[4][8];
            #pragma unroll
            for (int kk2 = 0; kk2 < 4; ++kk2) {
                const unsigned short* src =
                    Bb + (long long)(k0 + kb + kk2) * ldb + n0 + nb;
                if (n0 + nb + 8 <= N) {
                    *(ushort8v*)rv[kk2] = *(const ushort8v*)src;
                } else {
                    #pragma unroll
                    for (int j = 0; j < 8; ++j)
                        rv[kk2][j] = (n0 + nb + j < N) ? src[j] : 0;
                }
            }
            #pragma unroll
            for (int j = 0; j < 8; ++j) {
                ushort4v v4 = { rv[0][j], rv[1][j], rv[2][j], rv[3][j] };
                *(ushort4v*)&Bs[nb + j][kb] = v4;
            }
        }
        __syncthreads();

        #pragma unroll
        for (int ks = 0; ks < 2; ++ks) {
            bf16x8 bfr[2];
            #pragma unroll
            for (int nt = 0; nt < 2; ++nt)
                bfr[nt] = *(const bf16x8*)&Bs[w * 32 + nt * 16 + l15][ks * 32 + kq * 8];
            #pragma unroll
            for (int s = 0; s < 2; ++s) {
                #pragma unroll
                for (int mt = 0; mt < 2; ++mt) {
                    bf16x8 afr = *(const bf16x8*)&As[s][mt * 16 + l15][ks * 32 + kq * 8];
                    #pragma unroll
                    for (int nt = 0; nt < 2; ++nt)
                        acc[mt][nt] = __builtin_amdgcn_mfma_f32_16x16x32_bf16(
                            afr, bfr[nt], acc[mt][nt], 0, 0, 0);
                }
            }
        }
        __syncthreads();
    }

    float* Cb = C + (long long)b * cStride + (long long)blockIdx.y * partStride;
    #pragma unroll
    for (int mt = 0; mt < 2; ++mt) {
        #pragma unroll
        for (int i = 0; i < 4; ++i) {
            int m = mt * 16 + kq * 4 + i;
            if (m >= 20) continue;
            #pragma unroll
            for (int nt = 0; nt < 2; ++nt) {
                int n = n0 + w * 32 + nt * 16 + l15;
                if (n < N) Cb[(long long)m * N + n] = acc[mt][nt][i];
            }
        }
    }
}

// ---------------------------------------------------------------------------
// Parallel alpha-scan + spike over T=2048 per row -> bf16 (in-place overlay).
// ---------------------------------------------------------------------------
template <typename OutT>
__global__ __launch_bounds__(256) void scan_spike_T(
    const float* in, OutT* out, long long out_stride, int out_offset)
{
    const int row = blockIdx.x;
    const int tid = threadIdx.x;
    const float* x = in + (long long)row * 2048 + tid * 8;

    float v[8];
    #pragma unroll
    for (int k = 0; k < 8; ++k) v[k] = x[k];

    float y = 0.f;
    #pragma unroll
    for (int k = 0; k < 8; ++k) { y = ALPHA * y + v[k]; v[k] = y; }

    __shared__ float sc[256];
    float val = y;
    sc[tid] = val;
    float m = ALPHA8;
    for (int d = 1; d < 256; d <<= 1) {
        __syncthreads();
        float p = (tid >= d) ? sc[tid - d] : 0.f;
        __syncthreads();
        val += m * p;
        sc[tid] = val;
        m *= m;
    }
    __syncthreads();
    float carry = (tid > 0) ? sc[tid - 1] : 0.f;

    OutT* o = out + (long long)row * out_stride + out_offset + tid * 8;
    float ak = ALPHA;
    OutT ovals[8];
    #pragma unroll
    for (int k = 0; k < 8; ++k) {
        float yk = v[k] + ak * carry;
        ak *= ALPHA;
        bool sp = (yk >= THETA);
        if constexpr (sizeof(OutT) == 2)
            ovals[k] = sp ? (OutT)BF1 : (OutT)0;
        else
            ovals[k] = sp ? (OutT)1.0f : (OutT)0.0f;
    }
    #pragma unroll
    for (int k = 0; k < 8; ++k) o[k] = ovals[k];
}

// ---------------------------------------------------------------------------
// Final T-scan summing two split-K partials -> fp32 spikes to d_out.
// ---------------------------------------------------------------------------
__global__ __launch_bounds__(256) void scan_spike_T2(
    const float* __restrict__ in, long long partStride,
    float* __restrict__ out, long long out_stride)
{
    const int row = blockIdx.x;
    const int tid = threadIdx.x;
    const float* x = in + (long long)row * 2048 + tid * 8;

    float v[8];
    #pragma unroll
    for (int k = 0; k < 8; ++k) v[k] = x[k] + x[k + partStride];

    float y = 0.f;
    #pragma unroll
    for (int k = 0; k < 8; ++k) { y = ALPHA * y + v[k]; v[k] = y; }

    __shared__ float sc[256];
    float val = y;
    sc[tid] = val;
    float m = ALPHA8;
    for (int d = 1; d < 256; d <<= 1) {
        __syncthreads();
        float p = (tid >= d) ? sc[tid - d] : 0.f;
        __syncthreads();
        val += m * p;
        sc[tid] = val;
        m *= m;
    }
    __syncthreads();
    float carry = (tid > 0) ? sc[tid - 1] : 0.f;

    float* o = out + (long long)row * out_stride + tid * 8;
    float ak = ALPHA;
    #pragma unroll
    for (int k = 0; k < 8; ++k) {
        float yk = v[k] + ak * carry;
        ak *= ALPHA;
        o[k] = (yk >= THETA) ? 1.0f : 0.0f;
    }
}

// ---------------------------------------------------------------------------
// Branch-2 layer-1 scan: sum 4 split-K partials, alpha-scan in perm order,
// spike -> bf16.
// ---------------------------------------------------------------------------
__global__ __launch_bounds__(256) void scan_spike_C_perm(
    const float* __restrict__ in, const int* __restrict__ perm,
    unsigned short* __restrict__ out, int rows)
{
    __shared__ int p[156];
    for (int i = threadIdx.x; i < 156; i += blockDim.x) p[i] = perm[i];
    __syncthreads();

    int row = blockIdx.x * blockDim.x + threadIdx.x;
    if (row >= rows) return;
    const float* x = in + (long long)row * 156;
    unsigned short* o = out + (long long)row * 156;
    float y = 0.f;
    for (int c = 0; c < 156; ++c) {
        int pc = p[c];
        float s = x[pc] + x[pc + 2555904] + x[pc + 2 * 2555904] + x[pc + 3 * 2555904];
        y = ALPHA * y + s;
        o[c] = (y >= THETA) ? BF1 : 0;
    }
}

__global__ __launch_bounds__(256) void scan_spike_C_out(
    const float* __restrict__ in, float* __restrict__ out, int rows)
{
    int row = blockIdx.x * blockDim.x + threadIdx.x;
    if (row >= rows) return;
    const float* x = in + (long long)row * 156;
    float* o = out + (long long)row * 2204 + 2048;
    float y = 0.f;
    for (int c = 0; c < 156; ++c) {
        y = ALPHA * y + x[c];
        o[c] = (y >= THETA) ? 1.0f : 0.0f;
    }
}

// ---------------------------------------------------------------------------
// B=32, C_IN=156, T=2048, HID=512, OUT=20. Output [32,20,2204].
// ---------------------------------------------------------------------------
extern "C" void kernel_launch(void* const* d_in, const int* in_sizes, int n_in,
                              void* d_out, int out_size, void* d_ws, size_t ws_size,
                              hipStream_t stream)
{
    const float* In  = (const float*)d_in[0];  // [32][156][2048]
    const float* W1  = (const float*)d_in[1];  // [512][156]
    const float* W2  = (const float*)d_in[2];  // [20][512]
    const float* Wl1 = (const float*)d_in[3];  // [512][2048]
    const float* Wl2 = (const float*)d_in[4];  // [20][512]
    const int*  perm = (const int*)d_in[5];    // [156]
    float* out = (float*)d_out;                // [32][20][2204]

    float* ws = (float*)d_ws;
    // Layout (float offsets):
    float* D1  = ws;                                   // [16][512][2048] half-batch
    unsigned short* S1 = (unsigned short*)D1;          // overlay, row stride 4096 ush
    float* C2p = ws + 16777216LL;                      // [2][32][20][2048] partials
    unsigned short* Inbf = (unsigned short*)(ws + 19398656LL); // [4992][2048]
    unsigned short* InT  = (unsigned short*)(ws + 24510464LL); // [32][2048][160]
    unsigned short* W1p  = (unsigned short*)(ws + 29753344LL); // [2][512][160]
    unsigned short* W2p  = (unsigned short*)(ws + 29835264LL); // [2][32][512]
    unsigned short* Wl1p = (unsigned short*)(ws + 29851648LL); // [2][512][2048]
    unsigned short* Wl2p = (unsigned short*)(ws + 30900224LL); // [2][32][512]
    // total 30,916,608 floats = 123.7 MB
    // Branch-2 phase reuses the dead D1 region:
    float* Zp  = ws;                                   // [4][32][512][156] partials
    unsigned short* L1u = (unsigned short*)(ws + 10223616LL);  // [32][512][156] bf16
    float* Cl2 = ws + 11501568LL;                      // [32][20][156]

    dim3 blk(256);

    // ---- Preprocess ----
    prep_in<<<dim3(32, 3, 32), blk, 0, stream>>>(In, Inbf, InT);
    pack2_w<<<dim3(512), blk, 0, stream>>>(W1,  W1p,  512, 156,  160);
    pack2_w<<<dim3(32),  blk, 0, stream>>>(W2,  W2p,  20,  512,  512);
    pack2_w<<<dim3(512), blk, 0, stream>>>(Wl1, Wl1p, 512, 2048, 2048);
    pack2_w<<<dim3(32),  blk, 0, stream>>>(Wl2, Wl2p, 20,  512,  512);

    // ---- Branch 1 (two half-batches reusing D1) ----
    for (int h = 0; h < 2; ++h) {
        int b0 = h * 16;
        gemm1_mfma<<<dim3(16, 4, 16), blk, 0, stream>>>(W1p, InT, D1, b0);
        scan_spike_T<unsigned short><<<dim3(8192), blk, 0, stream>>>(D1, S1, 4096, 0);
        // split-K2: slices of 256, partials at C2p[0]/C2p[1]
        gemm2_mfma<<<dim3(16, 2, 16), blk, 0, stream>>>(
            W2p, S1, C2p + (long long)b0 * 20 * 2048, 2048, 4096,
            512LL * 4096, 20LL * 2048, 256, 1310720LL);
    }
    scan_spike_T2<<<dim3(640), blk, 0, stream>>>(C2p, 1310720LL, out, 2204);

    // ---- Branch 2 ----
    gemmL1_mfma<<<dim3(78, 8, 4), blk, 0, stream>>>(Wl1p, Inbf, Zp);
    scan_spike_C_perm<<<dim3(64), blk, 0, stream>>>(Zp, perm, L1u, 16384);
    gemm2_mfma<<<dim3(2, 1, 32), blk, 0, stream>>>(
        Wl2p, L1u, Cl2, 156, 156, 512LL * 156, 20LL * 156, 512, 0LL);
    scan_spike_C_out<<<dim3(3), blk, 0, stream>>>(Cl2, out, 640);

    (void)in_sizes; (void)n_in; (void)out_size; (void)ws_size;
}

// Round 6
// 300.611 us; speedup vs baseline: 1.4050x; 1.4050x over previous
//
#include <hip/hip_runtime.h>

// SLAYER constants
#define ALPHA  0.90483741803595952f   /* exp(-1/10) */
#define ALPHA8 0.44932896411722156f   /* exp(-0.8)  */
#define THETA  10.0f
#define BF1    ((unsigned short)0x3F80) /* 1.0f as bf16 */

typedef short   bf16x8 __attribute__((ext_vector_type(8)));
typedef float   f32x4  __attribute__((ext_vector_type(4)));
typedef float   f32x4v __attribute__((ext_vector_type(4)));
typedef unsigned short ushort4v __attribute__((ext_vector_type(4)));
typedef unsigned short ushort8v __attribute__((ext_vector_type(8)));

// RNE float -> bf16 bits
__device__ __forceinline__ unsigned short f2bf(float f) {
    unsigned int x = __float_as_uint(f);
    unsigned int r = (x + 0x7FFFu + ((x >> 16) & 1u)) >> 16;
    return (unsigned short)r;
}
__device__ __forceinline__ float bf2f(unsigned short h) {
    return __uint_as_float(((unsigned int)h) << 16);
}
// 2-way bf16 split: w ~= h0+h1 (residual ~2^-17 rel; spikes have huge margin)
__device__ __forceinline__ void split2(float w, unsigned short& h0,
                                       unsigned short& h1) {
    h0 = f2bf(w);          float r0 = w - bf2f(h0);
    h1 = f2bf(r0);
}

// ---------------------------------------------------------------------------
// Prep: In fp32 [32][156][2048] -> Inbf ushort [32*156][2048] (row-major bf16)
//                               -> InT  ushort [32][2048][160] (transposed, c pad 160)
// ---------------------------------------------------------------------------
__global__ __launch_bounds__(256) void prep_in(
    const float* __restrict__ In, unsigned short* __restrict__ Inbf,
    unsigned short* __restrict__ InT)
{
    __shared__ float Tile[64][65];
    const int t0 = blockIdx.x * 64;
    const int c0 = blockIdx.y * 64;
    const int b  = blockIdx.z;
    const int tid = threadIdx.x;

    #pragma unroll
    for (int s = 0; s < 4; ++s) {
        int id = tid + s * 256;
        int cc = id >> 4;
        int t4 = (id & 15) * 4;
        f32x4v v = {0.f, 0.f, 0.f, 0.f};
        if (c0 + cc < 156)
            v = *(const f32x4v*)(In + ((long long)(b * 156 + c0 + cc) * 2048 + t0 + t4));
        *(f32x4v*)&Tile[cc][t4] = v;
    }
    __syncthreads();

    #pragma unroll
    for (int s = 0; s < 2; ++s) {
        int id = tid + s * 256;
        int t  = id >> 3;
        int c8 = (id & 7) * 8;
        unsigned short r[8];
        #pragma unroll
        for (int j = 0; j < 8; ++j) r[j] = f2bf(Tile[c8 + j][t]);
        *(ushort8v*)(InT + (long long)b * 327680 + (long long)(t0 + t) * 160 + c0 + c8)
            = *(ushort8v*)r;
    }
    #pragma unroll
    for (int s = 0; s < 2; ++s) {
        int id = tid + s * 256;
        int cc = id >> 3;
        int t8 = (id & 7) * 8;
        if (c0 + cc < 156) {
            unsigned short r[8];
            #pragma unroll
            for (int j = 0; j < 8; ++j) r[j] = f2bf(Tile[cc][t8 + j]);
            *(ushort8v*)(Inbf + (long long)(b * 156 + c0 + cc) * 2048 + t0 + t8)
                = *(ushort8v*)r;
        }
    }
}

// ---------------------------------------------------------------------------
// Pack a weight matrix [M][K] fp32 into 2 bf16 split planes [2][Mp][Kp].
// ---------------------------------------------------------------------------
__global__ __launch_bounds__(256) void pack2_w(
    const float* __restrict__ W, unsigned short* __restrict__ P,
    int M, int K, int Kp)
{
    const int m = blockIdx.x;
    const int Mp = gridDim.x;
    for (int k = threadIdx.x; k < Kp; k += 256) {
        float v = (m < M && k < K) ? W[(long long)m * K + k] : 0.f;
        unsigned short h0, h1;
        split2(v, h0, h1);
        P[(long long)m * Kp + k] = h0;
        P[(long long)Mp * Kp + (long long)m * Kp + k] = h1;
    }
}

// ---------------------------------------------------------------------------
// Branch-1 GEMM1 (MFMA, packed split-2):
//   D1[z][m][n] = sum_c W1[m][c] * In[b0+z][c][n],  M=512, N=2048, K=160
// Tile 128x128, BK=32, 5 iters. grid (16 n, 4 m, 16 z).
// ---------------------------------------------------------------------------
__global__ __launch_bounds__(256) void gemm1_mfma(
    const unsigned short* __restrict__ W1p,
    const unsigned short* __restrict__ InT,
    float* __restrict__ D1, int b0)
{
    __shared__ alignas(16) unsigned short As[2][128][40];
    __shared__ alignas(16) unsigned short Bs[128][40];

    const int z  = blockIdx.z;
    const int m0 = blockIdx.y * 128;
    const int n0 = blockIdx.x * 128;
    const int tid  = threadIdx.x;
    const int lane = tid & 63, w = tid >> 6;
    const int wy = w >> 1, wx = w & 1;
    const int l15 = lane & 15, kq = lane >> 4;

    const unsigned short* Tb = InT + (long long)(b0 + z) * 327680;

    f32x4 acc[4][4] = {};

    for (int k0 = 0; k0 < 160; k0 += 32) {
        #pragma unroll
        for (int s = 0; s < 4; ++s) {
            int id = tid + s * 256;
            int pl = id >> 9, rem = id & 511;
            int m = rem >> 2, k8 = (rem & 3) * 8;
            ushort8v v = *(const ushort8v*)(W1p + (long long)pl * 81920 +
                                            (long long)(m0 + m) * 160 + k0 + k8);
            *(ushort8v*)&As[pl][m][k8] = v;
        }
        #pragma unroll
        for (int s = 0; s < 2; ++s) {
            int id = tid + s * 256;
            int t = id >> 2, c8 = (id & 3) * 8;
            ushort8v v = *(const ushort8v*)(Tb + (long long)(n0 + t) * 160 + k0 + c8);
            *(ushort8v*)&Bs[t][c8] = v;
        }
        __syncthreads();

        bf16x8 bfr[4];
        #pragma unroll
        for (int nt = 0; nt < 4; ++nt)
            bfr[nt] = *(const bf16x8*)&Bs[wx * 64 + nt * 16 + l15][kq * 8];
        #pragma unroll
        for (int s = 0; s < 2; ++s) {
            #pragma unroll
            for (int mt = 0; mt < 4; ++mt) {
                bf16x8 afr = *(const bf16x8*)&As[s][wy * 64 + mt * 16 + l15][kq * 8];
                #pragma unroll
                for (int nt = 0; nt < 4; ++nt)
                    acc[mt][nt] = __builtin_amdgcn_mfma_f32_16x16x32_bf16(
                        afr, bfr[nt], acc[mt][nt], 0, 0, 0);
            }
        }
        __syncthreads();
    }

    float* Db = D1 + (long long)z * 512 * 2048;
    #pragma unroll
    for (int mt = 0; mt < 4; ++mt) {
        #pragma unroll
        for (int i = 0; i < 4; ++i) {
            int m = m0 + wy * 64 + mt * 16 + kq * 4 + i;
            #pragma unroll
            for (int nt = 0; nt < 4; ++nt) {
                int n = n0 + wx * 64 + nt * 16 + l15;
                Db[(long long)m * 2048 + n] = acc[mt][nt][i];
            }
        }
    }
}

// ---------------------------------------------------------------------------
// Branch-2 GEMM1 (MFMA, packed split-2), batch merged into N, SPLIT-K x4:
//   Zp[s][c][b*512+m] (c-major!) = sum_{k in slice s} Wl1[m][k] * InF[n][k]
//   n = b*156+c.  M=512, N=4992, K=2048 (4 slices of 512).
// Tile 64m x 64n, BK=64. grid (78, 8, 4). Epilogue: LDS transpose -> coalesced
// c-major stores.
// ---------------------------------------------------------------------------
__global__ __launch_bounds__(256) void gemmL1_mfma(
    const unsigned short* __restrict__ Wl1p,  // [2][512][2048]
    const unsigned short* __restrict__ InF,   // [4992][2048] bf16
    float* __restrict__ Zp)                   // [4][156][16384] c-major partials
{
    __shared__ alignas(16) unsigned short As[2][64][72];
    __shared__ alignas(16) unsigned short Bs[64][72];

    const int n0  = blockIdx.x * 64;
    const int m0  = blockIdx.y * 64;
    const int ks0 = blockIdx.z * 512;
    const int tid  = threadIdx.x;
    const int lane = tid & 63, w = tid >> 6;
    const int wy = w >> 1, wx = w & 1;
    const int l15 = lane & 15, kq = lane >> 4;

    f32x4 acc[2][2] = {};

    for (int kk = 0; kk < 512; kk += 64) {
        const int k0 = ks0 + kk;
        #pragma unroll
        for (int s = 0; s < 4; ++s) {
            int id = tid + s * 256;
            int pl = id >> 9, rem = id & 511;
            int m = rem >> 3, k8 = (rem & 7) * 8;
            ushort8v v = *(const ushort8v*)(Wl1p + (long long)pl * 1048576 +
                                            (long long)(m0 + m) * 2048 + k0 + k8);
            *(ushort8v*)&As[pl][m][k8] = v;
        }
        #pragma unroll
        for (int s = 0; s < 2; ++s) {
            int id = tid + s * 256;
            int n = id >> 3, k8 = (id & 7) * 8;
            ushort8v v = *(const ushort8v*)(InF + (long long)(n0 + n) * 2048 + k0 + k8);
            *(ushort8v*)&Bs[n][k8] = v;
        }
        __syncthreads();

        #pragma unroll
        for (int ks = 0; ks < 2; ++ks) {
            bf16x8 bfr[2];
            #pragma unroll
            for (int nt = 0; nt < 2; ++nt)
                bfr[nt] = *(const bf16x8*)&Bs[wx * 32 + nt * 16 + l15][ks * 32 + kq * 8];
            #pragma unroll
            for (int s = 0; s < 2; ++s) {
                #pragma unroll
                for (int mt = 0; mt < 2; ++mt) {
                    bf16x8 afr = *(const bf16x8*)&As[s][wy * 32 + mt * 16 + l15][ks * 32 + kq * 8];
                    #pragma unroll
                    for (int nt = 0; nt < 2; ++nt)
                        acc[mt][nt] = __builtin_amdgcn_mfma_f32_16x16x32_bf16(
                            afr, bfr[nt], acc[mt][nt], 0, 0, 0);
                }
            }
        }
        __syncthreads();
    }

    // Epilogue: transpose tile through LDS (reuse As; 64x65 floats = 16.6KB
    // <= 18.4KB), then store c-major coalesced.
    float* T = (float*)As;
    #pragma unroll
    for (int mt = 0; mt < 2; ++mt) {
        #pragma unroll
        for (int i = 0; i < 4; ++i) {
            int mL = wy * 32 + mt * 16 + kq * 4 + i;
            #pragma unroll
            for (int nt = 0; nt < 2; ++nt) {
                int nL = wx * 32 + nt * 16 + l15;
                T[mL * 65 + nL] = acc[mt][nt][i];
            }
        }
    }
    __syncthreads();

    float* Zs = Zp + (long long)blockIdx.z * 2555904;
    #pragma unroll
    for (int s2 = 0; s2 < 16; ++s2) {
        int id = tid + s2 * 256;       // 0..4095
        int cL = id >> 6;              // local n 0..63
        int mL = id & 63;
        int n = n0 + cL;
        int bb = n / 156, cc = n - bb * 156;
        Zs[(long long)cc * 16384 + bb * 512 + m0 + mL] = T[mL * 65 + cL];
    }
}

// ---------------------------------------------------------------------------
// GEMM2 (MFMA, packed split-2 A, optional split-K via blockIdx.y) for branch 1:
//   Cpart[y][b][m][n] = sum_{k in slice y} A[m][k] * Bsp[b][k][n]
// Tile 32m x 128n, BK=64.
// ---------------------------------------------------------------------------
__global__ __launch_bounds__(256) void gemm2_mfma(
    const unsigned short* __restrict__ Ap,
    const unsigned short* __restrict__ Bsp,
    float* __restrict__ C,
    int N, int ldb, long long bStrideB, long long cStride,
    int kPerSlice, long long partStride)
{
    __shared__ alignas(16) unsigned short As[2][32][72];
    __shared__ alignas(16) unsigned short Bs[128][72];

    const int b   = blockIdx.z;
    const int n0  = blockIdx.x * 128;
    const int ks0 = blockIdx.y * kPerSlice;
    const int tid  = threadIdx.x;
    const int lane = tid & 63, w = tid >> 6;
    const int l15 = lane & 15, kq = lane >> 4;

    const unsigned short* Bb = Bsp + (long long)b * bStrideB;

    f32x4 acc[2][2] = {};

    for (int kk = 0; kk < kPerSlice; kk += 64) {
        const int k0 = ks0 + kk;
        #pragma unroll
        for (int s = 0; s < 2; ++s) {
            int id = tid + s * 256;
            int pl = id >> 8, rem = id & 255;
            int m = rem >> 3, k8 = (rem & 7) * 8;
            ushort8v v = *(const ushort8v*)(Ap + (long long)pl * 16384 +
                                            (long long)m * 512 + k0 + k8);
            *(ushort8v*)&As[pl][m][k8] = v;
        }
        {
            int kb = (tid >> 4) * 4;
            int nb = (tid & 15) * 8;
            unsigned short rv[4][8];
            #pragma unroll
            for (int kk2 = 0; kk2 < 4; ++kk2) {
                const unsigned short* src =
                    Bb + (long long)(k0 + kb + kk2) * ldb + n0 + nb;
                *(ushort8v*)rv[kk2] = *(const ushort8v*)src;
            }
            #pragma unroll
            for (int j = 0; j < 8; ++j) {
                ushort4v v4 = { rv[0][j], rv[1][j], rv[2][j], rv[3][j] };
                *(ushort4v*)&Bs[nb + j][kb] = v4;
            }
        }
        __syncthreads();

        #pragma unroll
        for (int ks = 0; ks < 2; ++ks) {
            bf16x8 bfr[2];
            #pragma unroll
            for (int nt = 0; nt < 2; ++nt)
                bfr[nt] = *(const bf16x8*)&Bs[w * 32 + nt * 16 + l15][ks * 32 + kq * 8];
            #pragma unroll
            for (int s = 0; s < 2; ++s) {
                #pragma unroll
                for (int mt = 0; mt < 2; ++mt) {
                    bf16x8 afr = *(const bf16x8*)&As[s][mt * 16 + l15][ks * 32 + kq * 8];
                    #pragma unroll
                    for (int nt = 0; nt < 2; ++nt)
                        acc[mt][nt] = __builtin_amdgcn_mfma_f32_16x16x32_bf16(
                            afr, bfr[nt], acc[mt][nt], 0, 0, 0);
                }
            }
        }
        __syncthreads();
    }

    float* Cb = C + (long long)b * cStride + (long long)blockIdx.y * partStride;
    #pragma unroll
    for (int mt = 0; mt < 2; ++mt) {
        #pragma unroll
        for (int i = 0; i < 4; ++i) {
            int m = mt * 16 + kq * 4 + i;
            if (m >= 20) continue;
            #pragma unroll
            for (int nt = 0; nt < 2; ++nt) {
                int n = n0 + w * 32 + nt * 16 + l15;
                Cb[(long long)m * N + n] = acc[mt][nt][i];
            }
        }
    }
}

// ---------------------------------------------------------------------------
// Branch-2 layer-2 GEMM: C[b][m][c] = sum_h Wl2[m][h] * L1T[c][b*512+h]
// B is k-contiguous in L1T. Tile 32m x 128n(c), BK=64. grid (2, 1, 32).
// ---------------------------------------------------------------------------
__global__ __launch_bounds__(256) void gemm2B_mfma(
    const unsigned short* __restrict__ Ap,   // [2][32][512] Wl2 planes
    const unsigned short* __restrict__ L1T,  // [156][16384] bf16 spikes
    float* __restrict__ Cl2)                 // [32][20][156]
{
    __shared__ alignas(16) unsigned short As[2][32][72];
    __shared__ alignas(16) unsigned short Bs[128][72];

    const int b  = blockIdx.z;
    const int n0 = blockIdx.x * 128;
    const int tid  = threadIdx.x;
    const int lane = tid & 63, w = tid >> 6;
    const int l15 = lane & 15, kq = lane >> 4;

    f32x4 acc[2][2] = {};

    for (int k0 = 0; k0 < 512; k0 += 64) {
        #pragma unroll
        for (int s = 0; s < 2; ++s) {
            int id = tid + s * 256;
            int pl = id >> 8, rem = id & 255;
            int m = rem >> 3, k8 = (rem & 7) * 8;
            ushort8v v = *(const ushort8v*)(Ap + (long long)pl * 16384 +
                                            (long long)m * 512 + k0 + k8);
            *(ushort8v*)&As[pl][m][k8] = v;
        }
        // B: rows n = c, k contiguous
        #pragma unroll
        for (int s = 0; s < 4; ++s) {
            int id = tid + s * 256;
            int n = id >> 3, k8 = (id & 7) * 8;
            ushort8v v = {0,0,0,0,0,0,0,0};
            if (n0 + n < 156)
                v = *(const ushort8v*)(L1T + (long long)(n0 + n) * 16384 +
                                       b * 512 + k0 + k8);
            *(ushort8v*)&Bs[n][k8] = v;
        }
        __syncthreads();

        #pragma unroll
        for (int ks = 0; ks < 2; ++ks) {
            bf16x8 bfr[2];
            #pragma unroll
            for (int nt = 0; nt < 2; ++nt)
                bfr[nt] = *(const bf16x8*)&Bs[w * 32 + nt * 16 + l15][ks * 32 + kq * 8];
            #pragma unroll
            for (int s = 0; s < 2; ++s) {
                #pragma unroll
                for (int mt = 0; mt < 2; ++mt) {
                    bf16x8 afr = *(const bf16x8*)&As[s][mt * 16 + l15][ks * 32 + kq * 8];
                    #pragma unroll
                    for (int nt = 0; nt < 2; ++nt)
                        acc[mt][nt] = __builtin_amdgcn_mfma_f32_16x16x32_bf16(
                            afr, bfr[nt], acc[mt][nt], 0, 0, 0);
                }
            }
        }
        __syncthreads();
    }

    float* Cb = Cl2 + (long long)b * 20 * 156;
    #pragma unroll
    for (int mt = 0; mt < 2; ++mt) {
        #pragma unroll
        for (int i = 0; i < 4; ++i) {
            int m = mt * 16 + kq * 4 + i;
            if (m >= 20) continue;
            #pragma unroll
            for (int nt = 0; nt < 2; ++nt) {
                int n = n0 + w * 32 + nt * 16 + l15;
                if (n < 156) Cb[(long long)m * 156 + n] = acc[mt][nt][i];
            }
        }
    }
}

// ---------------------------------------------------------------------------
// Parallel alpha-scan + spike over T=2048 per row -> bf16 (in-place overlay).
// ---------------------------------------------------------------------------
template <typename OutT>
__global__ __launch_bounds__(256) void scan_spike_T(
    const float* in, OutT* out, long long out_stride, int out_offset)
{
    const int row = blockIdx.x;
    const int tid = threadIdx.x;
    const float* x = in + (long long)row * 2048 + tid * 8;

    float v[8];
    #pragma unroll
    for (int k = 0; k < 8; ++k) v[k] = x[k];

    float y = 0.f;
    #pragma unroll
    for (int k = 0; k < 8; ++k) { y = ALPHA * y + v[k]; v[k] = y; }

    __shared__ float sc[256];
    float val = y;
    sc[tid] = val;
    float m = ALPHA8;
    for (int d = 1; d < 256; d <<= 1) {
        __syncthreads();
        float p = (tid >= d) ? sc[tid - d] : 0.f;
        __syncthreads();
        val += m * p;
        sc[tid] = val;
        m *= m;
    }
    __syncthreads();
    float carry = (tid > 0) ? sc[tid - 1] : 0.f;

    OutT* o = out + (long long)row * out_stride + out_offset + tid * 8;
    float ak = ALPHA;
    OutT ovals[8];
    #pragma unroll
    for (int k = 0; k < 8; ++k) {
        float yk = v[k] + ak * carry;
        ak *= ALPHA;
        bool sp = (yk >= THETA);
        if constexpr (sizeof(OutT) == 2)
            ovals[k] = sp ? (OutT)BF1 : (OutT)0;
        else
            ovals[k] = sp ? (OutT)1.0f : (OutT)0.0f;
    }
    #pragma unroll
    for (int k = 0; k < 8; ++k) o[k] = ovals[k];
}

// ---------------------------------------------------------------------------
// Final T-scan summing two split-K partials -> fp32 spikes to d_out.
// ---------------------------------------------------------------------------
__global__ __launch_bounds__(256) void scan_spike_T2(
    const float* __restrict__ in, long long partStride,
    float* __restrict__ out, long long out_stride)
{
    const int row = blockIdx.x;
    const int tid = threadIdx.x;
    const float* x = in + (long long)row * 2048 + tid * 8;

    float v[8];
    #pragma unroll
    for (int k = 0; k < 8; ++k) v[k] = x[k] + x[k + partStride];

    float y = 0.f;
    #pragma unroll
    for (int k = 0; k < 8; ++k) { y = ALPHA * y + v[k]; v[k] = y; }

    __shared__ float sc[256];
    float val = y;
    sc[tid] = val;
    float m = ALPHA8;
    for (int d = 1; d < 256; d <<= 1) {
        __syncthreads();
        float p = (tid >= d) ? sc[tid - d] : 0.f;
        __syncthreads();
        val += m * p;
        sc[tid] = val;
        m *= m;
    }
    __syncthreads();
    float carry = (tid > 0) ? sc[tid - 1] : 0.f;

    float* o = out + (long long)row * out_stride + tid * 8;
    float ak = ALPHA;
    #pragma unroll
    for (int k = 0; k < 8; ++k) {
        float yk = v[k] + ak * carry;
        ak *= ALPHA;
        o[k] = (yk >= THETA) ? 1.0f : 0.0f;
    }
}

// ---------------------------------------------------------------------------
// Branch-2 layer-1 scan, c-major: sum 4 partials Zp[s][c][row] (coalesced),
// scan over c in perm order via LDS, write spikes c-major to L1T[c][row].
// 256 blocks x 64 rows.
// ---------------------------------------------------------------------------
__global__ __launch_bounds__(256) void scan_sum4_perm(
    const float* __restrict__ Zp, const int* __restrict__ perm,
    unsigned short* __restrict__ L1T)
{
    __shared__ float Xs[156][64];   // 39.9 KB
    __shared__ int p[156];

    const int r0  = blockIdx.x * 64;
    const int tid = threadIdx.x;
    for (int i = tid; i < 156; i += 256) p[i] = perm[i];

    const int row = tid & 63;
    const int cq  = tid >> 6;       // 0..3
    #pragma unroll
    for (int it = 0; it < 39; ++it) {
        int c = it * 4 + cq;
        long long base = (long long)c * 16384 + r0 + row;
        float s = Zp[base] + Zp[base + 2555904] +
                  Zp[base + 2 * 2555904] + Zp[base + 3 * 2555904];
        Xs[c][row] = s;
    }
    __syncthreads();

    if (tid < 64) {
        float y = 0.f;
        for (int c = 0; c < 156; ++c) {
            y = ALPHA * y + Xs[p[c]][tid];
            L1T[(long long)c * 16384 + r0 + tid] = (y >= THETA) ? BF1 : 0;
        }
    }
}

__global__ __launch_bounds__(256) void scan_spike_C_out(
    const float* __restrict__ in, float* __restrict__ out, int rows)
{
    int row = blockIdx.x * blockDim.x + threadIdx.x;
    if (row >= rows) return;
    const float* x = in + (long long)row * 156;
    float* o = out + (long long)row * 2204 + 2048;
    float y = 0.f;
    for (int c = 0; c < 156; ++c) {
        y = ALPHA * y + x[c];
        o[c] = (y >= THETA) ? 1.0f : 0.0f;
    }
}

// ---------------------------------------------------------------------------
// B=32, C_IN=156, T=2048, HID=512, OUT=20. Output [32,20,2204].
// ---------------------------------------------------------------------------
extern "C" void kernel_launch(void* const* d_in, const int* in_sizes, int n_in,
                              void* d_out, int out_size, void* d_ws, size_t ws_size,
                              hipStream_t stream)
{
    const float* In  = (const float*)d_in[0];  // [32][156][2048]
    const float* W1  = (const float*)d_in[1];  // [512][156]
    const float* W2  = (const float*)d_in[2];  // [20][512]
    const float* Wl1 = (const float*)d_in[3];  // [512][2048]
    const float* Wl2 = (const float*)d_in[4];  // [20][512]
    const int*  perm = (const int*)d_in[5];    // [156]
    float* out = (float*)d_out;                // [32][20][2204]

    float* ws = (float*)d_ws;
    // Layout (float offsets):
    float* D1  = ws;                                   // [16][512][2048] half-batch
    unsigned short* S1 = (unsigned short*)D1;          // overlay, row stride 4096 ush
    float* C2p = ws + 16777216LL;                      // [2][32][20][2048] partials
    unsigned short* Inbf = (unsigned short*)(ws + 19398656LL); // [4992][2048]
    unsigned short* InT  = (unsigned short*)(ws + 24510464LL); // [32][2048][160]
    unsigned short* W1p  = (unsigned short*)(ws + 29753344LL); // [2][512][160]
    unsigned short* W2p  = (unsigned short*)(ws + 29835264LL); // [2][32][512]
    unsigned short* Wl1p = (unsigned short*)(ws + 29851648LL); // [2][512][2048]
    unsigned short* Wl2p = (unsigned short*)(ws + 30900224LL); // [2][32][512]
    // total 30,916,608 floats = 123.7 MB
    // Branch-2 phase reuses the dead D1 region:
    float* Zp = ws;                                    // [4][156][16384] c-major
    unsigned short* L1T = (unsigned short*)(ws + 10223616LL);  // [156][16384] bf16
    float* Cl2 = ws + 11501568LL;                      // [32][20][156]

    dim3 blk(256);

    // ---- Preprocess ----
    prep_in<<<dim3(32, 3, 32), blk, 0, stream>>>(In, Inbf, InT);
    pack2_w<<<dim3(512), blk, 0, stream>>>(W1,  W1p,  512, 156,  160);
    pack2_w<<<dim3(32),  blk, 0, stream>>>(W2,  W2p,  20,  512,  512);
    pack2_w<<<dim3(512), blk, 0, stream>>>(Wl1, Wl1p, 512, 2048, 2048);
    pack2_w<<<dim3(32),  blk, 0, stream>>>(Wl2, Wl2p, 20,  512,  512);

    // ---- Branch 1 (two half-batches reusing D1) ----
    for (int h = 0; h < 2; ++h) {
        int b0 = h * 16;
        gemm1_mfma<<<dim3(16, 4, 16), blk, 0, stream>>>(W1p, InT, D1, b0);
        scan_spike_T<unsigned short><<<dim3(8192), blk, 0, stream>>>(D1, S1, 4096, 0);
        gemm2_mfma<<<dim3(16, 2, 16), blk, 0, stream>>>(
            W2p, S1, C2p + (long long)b0 * 20 * 2048, 2048, 4096,
            512LL * 4096, 20LL * 2048, 256, 1310720LL);
    }
    scan_spike_T2<<<dim3(640), blk, 0, stream>>>(C2p, 1310720LL, out, 2204);

    // ---- Branch 2 ----
    gemmL1_mfma<<<dim3(78, 8, 4), blk, 0, stream>>>(Wl1p, Inbf, Zp);
    scan_sum4_perm<<<dim3(256), blk, 0, stream>>>(Zp, perm, L1T);
    gemm2B_mfma<<<dim3(2, 1, 32), blk, 0, stream>>>(Wl2p, L1T, Cl2);
    scan_spike_C_out<<<dim3(3), blk, 0, stream>>>(Cl2, out, 640);

    (void)in_sizes; (void)n_in; (void)out_size; (void)ws_size;
}